// Round 2
// baseline (430.791 us; speedup 1.0000x reference)
//
#include <hip/hip_runtime.h>
#include <hip/hip_bf16.h>

#define NN 1048576
#define NG 16384
#define DD 128
#define GRID 2048

typedef __bf16 bf16x8 __attribute__((ext_vector_type(8)));
typedef float f32x4 __attribute__((ext_vector_type(4)));
typedef unsigned short us8v __attribute__((ext_vector_type(8)));

__device__ __forceinline__ unsigned short f2bf(float f) {
    unsigned int u = __float_as_uint(f);
    u += 0x7FFFu + ((u >> 16) & 1u);
    return (unsigned short)(u >> 16);
}

__global__ void prep_kernel(const int* __restrict__ gid, const float* __restrict__ W,
                            int* __restrict__ starts, unsigned short* __restrict__ Wl) {
    int t = blockIdx.x * 256 + threadIdx.x;
    if (t <= NG) {
        int lo = 0, hi = NN;
        while (lo < hi) { int mid = (lo + hi) >> 1; if (gid[mid] < t) lo = mid + 1; else hi = mid; }
        starts[t] = lo;
    }
    if (t < DD * DD) {
        // fragment-ordered B layout: Wl[((n*4+kk)*64 + l)*8 + e] = bf16(W[k][col]),
        // k = kk*32 + (l>>4)*8 + e, col = n*16 + (l&15)
        int e = t & 7, l = (t >> 3) & 63, kk = (t >> 9) & 3, n = t >> 11;
        int k = kk * 32 + (l >> 4) * 8 + e;
        int col = n * 16 + (l & 15);
        Wl[t] = f2bf(W[k * DD + col]);
    }
}

__global__ __launch_bounds__(256, 3) void fused_kernel(
    const float* __restrict__ x, const int* __restrict__ starts,
    const unsigned short* __restrict__ Wl,
    const float* __restrict__ b_enc, const float* __restrict__ w_q1,
    const float* __restrict__ b_q1, const float* __restrict__ w_q2,
    const float* __restrict__ b_q2, float* __restrict__ out) {

    __shared__ unsigned short Wl_lds[DD * DD];   // 32 KB, fragment-ordered (lane-linear)
    __shared__ float s1s[64], s2s[64];           // per-chunk scores
    __shared__ float scratch[12 * DD];           // 6 KB cross-wave writeout

    const int t = threadIdx.x;
    const int w = t >> 6, l = t & 63;
    const int lr = l & 15, lk = l >> 4;

    for (int i = t; i < (DD * DD) / 8; i += 256)
        *(us8v*)&Wl_lds[i * 8] = *(const us8v*)&Wl[i * 8];

    float br[8], w1r[8], w2r[8];
#pragma unroll
    for (int n = 0; n < 8; ++n) {
        br[n]  = b_enc[n * 16 + lr];
        w1r[n] = w_q1[n * 16 + lr];
        w2r[n] = w_q2[n * 16 + lr];
    }
    const float bq1 = b_q1[0], bq2 = b_q2[0];
    __syncthreads();

    int cg = blockIdx.x;
    int cseg0 = starts[cg], cseg1 = starts[cg + 1];
    int cc0 = cseg0;

    float4 pf[8];
    {   // initial prefetch
        const int grow = cc0 + w * 16 + lr;
        const float* xp = x + (size_t)grow * DD + lk * 8;
        const bool v = grow < cseg1;
        const float4 zz = {0.f, 0.f, 0.f, 0.f};
#pragma unroll
        for (int kk = 0; kk < 4; ++kk) {
            pf[2 * kk]     = v ? *(const float4*)(xp + kk * 32)     : zz;
            pf[2 * kk + 1] = v ? *(const float4*)(xp + kk * 32 + 4) : zz;
        }
    }

    float m1 = -1e30f, m2 = -1e30f, z1 = 0.f, z2 = 0.f;
    float ka[8], q1a[8], q2a[8];
#pragma unroll
    for (int n = 0; n < 8; ++n) { ka[n] = 0.f; q1a[n] = 0.f; q2a[n] = 0.f; }

    while (true) {
        // ---- consume prefetch: fp32 -> bf16 A-fragments ----
        bf16x8 afr[4];
#pragma unroll
        for (int kk = 0; kk < 4; ++kk) {
            float4 a = pf[2 * kk], b2 = pf[2 * kk + 1];
            us8v uv;
            uv[0] = f2bf(a.x); uv[1] = f2bf(a.y); uv[2] = f2bf(a.z); uv[3] = f2bf(a.w);
            uv[4] = f2bf(b2.x); uv[5] = f2bf(b2.y); uv[6] = f2bf(b2.z); uv[7] = f2bf(b2.w);
            afr[kk] = __builtin_bit_cast(bf16x8, uv);
        }

        // ---- compute next chunk coords + issue prefetch (hides HBM latency) ----
        const bool lastChunk = (cc0 + 64 >= cseg1);
        int ng = cg, nc0 = cc0 + 64, nseg0 = cseg0, nseg1 = cseg1;
        if (lastChunk) {
            ng = cg + GRID;
            if (ng < NG) { nseg0 = starts[ng]; nc0 = nseg0; nseg1 = starts[ng + 1]; }
            else ng = -1;
        }
        if (ng >= 0) {
            const int grow = nc0 + w * 16 + lr;
            const float* xp = x + (size_t)grow * DD + lk * 8;
            const bool v = grow < nseg1;
            const float4 zz = {0.f, 0.f, 0.f, 0.f};
#pragma unroll
            for (int kk = 0; kk < 4; ++kk) {
                pf[2 * kk]     = v ? *(const float4*)(xp + kk * 32)     : zz;
                pf[2 * kk + 1] = v ? *(const float4*)(xp + kk * 32 + 4) : zz;
            }
        }

        // ---- MFMA: h-tile in registers; B from LDS, lane-linear (conflict-free) ----
        f32x4 acc[8];
#pragma unroll
        for (int n = 0; n < 8; ++n) { acc[n][0] = 0.f; acc[n][1] = 0.f; acc[n][2] = 0.f; acc[n][3] = 0.f; }
#pragma unroll
        for (int n = 0; n < 8; ++n)
#pragma unroll
            for (int kk = 0; kk < 4; ++kk) {
                bf16x8 bfr = *(const bf16x8*)&Wl_lds[((n * 4 + kk) * 64 + l) * 8];
                acc[n] = __builtin_amdgcn_mfma_f32_16x16x32_bf16(afr[kk], bfr, acc[n], 0, 0, 0);
            }

        // ---- bias + relu in regs; per-thread score partials ----
        float p1[4] = {0.f, 0.f, 0.f, 0.f}, p2[4] = {0.f, 0.f, 0.f, 0.f};
#pragma unroll
        for (int n = 0; n < 8; ++n)
#pragma unroll
            for (int j = 0; j < 4; ++j) {
                float hv = fmaxf(acc[n][j] + br[n], 0.f);
                acc[n][j] = hv;                 // acc now holds h
                p1[j] += hv * w1r[n];
                p2[j] += hv * w2r[n];
            }
        // butterfly over lr (lanes differing in bits 0..3) -> full 128-col dot
#pragma unroll
        for (int j = 0; j < 4; ++j)
#pragma unroll
            for (int d = 1; d < 16; d <<= 1) {
                p1[j] += __shfl_xor(p1[j], d);
                p2[j] += __shfl_xor(p2[j], d);
            }

        __syncthreads();   // prev chunk's s-reads / prev graph's scratch reads done
        if (lr == 0) {
#pragma unroll
            for (int j = 0; j < 4; ++j) {
                const int row = w * 16 + lk * 4 + j;
                const bool v = (cc0 + row) < cseg1;
                s1s[row] = v ? p1[j] + bq1 : -1e30f;
                s2s[row] = v ? p2[j] + bq2 : -1e30f;
            }
        }
        __syncthreads();

        // ---- online softmax state (all waves redundantly, identical) ----
        float v1 = s1s[l], v2 = s2s[l];
        float r1 = v1, r2 = v2;
#pragma unroll
        for (int d = 1; d < 64; d <<= 1) {
            r1 = fmaxf(r1, __shfl_xor(r1, d));
            r2 = fmaxf(r2, __shfl_xor(r2, d));
        }
        const float nm1 = fmaxf(m1, r1), nm2 = fmaxf(m2, r2);
        const float sc1 = __expf(m1 - nm1), sc2 = __expf(m2 - nm2);
        float cz1 = __expf(v1 - nm1), cz2 = __expf(v2 - nm2);
#pragma unroll
        for (int d = 1; d < 64; d <<= 1) { cz1 += __shfl_xor(cz1, d); cz2 += __shfl_xor(cz2, d); }
        z1 = z1 * sc1 + cz1; z2 = z2 * sc2 + cz2;
        m1 = nm1; m2 = nm2;

        // ---- accumulate keys/q1/q2 in registers ----
        float e1j[4], e2j[4];
#pragma unroll
        for (int j = 0; j < 4; ++j) {
            const bool v = (cc0 + w * 16 + lk * 4 + j) < cseg1;
            e1j[j] = v ? __expf(p1[j] + bq1 - nm1) : 0.f;
            e2j[j] = v ? __expf(p2[j] + bq2 - nm2) : 0.f;
        }
#pragma unroll
        for (int n = 0; n < 8; ++n) {
            float kaa = 0.f, q1aa = 0.f, q2aa = 0.f;
#pragma unroll
            for (int j = 0; j < 4; ++j) {
                const float hv = acc[n][j];
                const bool v = (cc0 + w * 16 + lk * 4 + j) < cseg1;
                kaa  += v ? hv : 0.f;
                q1aa += e1j[j] * hv;
                q2aa += e2j[j] * hv;
            }
            ka[n] += kaa;
            q1a[n] = q1a[n] * sc1 + q1aa;
            q2a[n] = q2a[n] * sc2 + q2aa;
        }

        if (lastChunk) {
            // reduce over lk (lanes differing in bits 4,5)
#pragma unroll
            for (int n = 0; n < 8; ++n)
#pragma unroll
                for (int d = 16; d < 64; d <<= 1) {
                    ka[n]  += __shfl_xor(ka[n],  d);
                    q1a[n] += __shfl_xor(q1a[n], d);
                    q2a[n] += __shfl_xor(q2a[n], d);
                }
            __syncthreads();
            if (lk == 0) {
#pragma unroll
                for (int n = 0; n < 8; ++n) {
                    scratch[(w * 3 + 0) * DD + n * 16 + lr] = ka[n];
                    scratch[(w * 3 + 1) * DD + n * 16 + lr] = q1a[n];
                    scratch[(w * 3 + 2) * DD + n * 16 + lr] = q2a[n];
                }
            }
            __syncthreads();
            if (t < DD) {
                const float kt  = scratch[0 * DD + t] + scratch[3 * DD + t] + scratch[6 * DD + t] + scratch[9 * DD + t];
                const float q1t = scratch[1 * DD + t] + scratch[4 * DD + t] + scratch[7 * DD + t] + scratch[10 * DD + t];
                const float q2t = scratch[2 * DD + t] + scratch[5 * DD + t] + scratch[8 * DD + t] + scratch[11 * DD + t];
                const int cnt = cseg1 - cseg0;
                out[(size_t)cg * DD + t]               = kt / fmaxf((float)cnt, 1.f);
                out[(size_t)(NG + cg) * DD + t]        = q1t / fmaxf(z1, 1e-12f);
                out[(size_t)(2 * NG + cg) * DD + t]    = q2t / fmaxf(z2, 1e-12f);
            }
            if (ng < 0) break;
            cg = ng; cseg0 = nseg0; cseg1 = nseg1; cc0 = nc0;
            m1 = -1e30f; m2 = -1e30f; z1 = 0.f; z2 = 0.f;
#pragma unroll
            for (int n = 0; n < 8; ++n) { ka[n] = 0.f; q1a[n] = 0.f; q2a[n] = 0.f; }
        } else {
            cc0 = nc0;
        }
    }
}

extern "C" void kernel_launch(void* const* d_in, const int* in_sizes, int n_in,
                              void* d_out, int out_size, void* d_ws, size_t ws_size,
                              hipStream_t stream) {
    const float* x     = (const float*)d_in[0];
    const int*   gid   = (const int*)d_in[1];
    const float* W     = (const float*)d_in[2];
    const float* b_enc = (const float*)d_in[3];
    const float* w_q1  = (const float*)d_in[4];
    const float* b_q1  = (const float*)d_in[5];
    const float* w_q2  = (const float*)d_in[6];
    const float* b_q2  = (const float*)d_in[7];
    float* out = (float*)d_out;

    int* starts        = (int*)d_ws;                                // (NG+1) ints
    unsigned short* Wl = (unsigned short*)((char*)d_ws + 131072);   // 128*128 bf16, fragment-ordered

    prep_kernel<<<65, 256, 0, stream>>>(gid, W, starts, Wl);
    fused_kernel<<<GRID, 256, 0, stream>>>(x, starts, Wl, b_enc, w_q1, b_q1, w_q2, b_q2, out);
}